// Round 9
// baseline (94.742 us; speedup 1.0000x reference)
//
#include <hip/hip_runtime.h>

// PrRoIPool2D forward, MI355X. B=8, C=256, H=W=48, R=300, 7x7 bins, scale=1/16.
// R9: R8 + LDS bank-conflict fix.
//  - patch row stride 252 floats (mod 32 = 28, was 224 = 0) with a 4-float pad
//    per 32-float column group: column c at (c>>2)*36 + (c&3)*8. Both the j and
//    i address components now sweep banks instead of collapsing onto 4.
//  - rs pw-stride 188 (mod 32 = 28, was 184 = 24).
//  P2 precomputes per-(pw,tap) column offsets in s_xoff. 28.9 KB LDS, 5 blk/CU.

#define PH 7
#define PW 7
#define NBINS 49
#define SCALE 0.0625f
#define CH 256
#define FH 48
#define FW 48
#define RNUM 300
#define CB 8                 // channels per block
#define QN 2                 // channel quads per block
#define MAXJ 23              // max patch rows
#define RS 252               // patch row stride (floats): 7 groups * 36
#define RSJ 188              // rs pw-stride (floats): 23*8 + 4 pad

__device__ __forceinline__ float hat_int(float x, float g) {
    float t = x - (g - 1.0f);
    if (t <= 0.0f) return 0.0f;
    if (t <= 1.0f) return 0.5f * t * t;
    if (t <= 2.0f) { float u = 2.0f - t; return 1.0f - 0.5f * u * u; }
    return 1.0f;
}

__global__ __launch_bounds__(256)
void prroi_fused(const float* __restrict__ feat,
                 const float* __restrict__ rois,
                 float* __restrict__ out) {
    const int cblk = blockIdx.x;        // 0..31
    const int r    = blockIdx.y;        // 0..299
    const int c0   = cblk * CB;
    const int tid  = threadIdx.x;

    __shared__ float patch[MAXJ * RS];          // [j][col-padded][c8] 23184 B
    __shared__ float rs[PW * RSJ];              // [pw][j][c8] padded  5264 B
    __shared__ float s_wy[PH][6];
    __shared__ float s_wx[PW][6];
    __shared__ int   s_xoff[PW][6];             // per-tap column offsets in row
    __shared__ int   s_bj[PH];                  // window base (patch-rel rows)

    // ---- uniform ROI params ----
    const float* roi = rois + r * 5;
    const int   b  = (int)roi[0];
    const float x1 = roi[1] * SCALE, y1 = roi[2] * SCALE;
    const float x2 = roi[3] * SCALE, y2 = roi[4] * SCALE;
    const float roi_w = fmaxf(x2 - x1, 0.0f), roi_h = fmaxf(y2 - y1, 0.0f);
    const float bin_w = roi_w / (float)PW, bin_h = roi_h / (float)PH;
    const float area = bin_w * bin_h;
    const float inv_area = (area > 0.0f) ? (1.0f / area) : 0.0f;

    const float ylo = fminf(y1, y2), yhi = fmaxf(y1, y2);
    const float xlo = fminf(x1, x2), xhi = fmaxf(x1, x2);
    const int j1 = min(FH - 1, (int)floorf(yhi) + 1);
    const int i1 = min(FW - 1, (int)floorf(xhi) + 1);
    const int J0 = min(max(0, (int)floorf(ylo) - 1), FH - 6);
    const int I0 = min(max(0, (int)floorf(xlo) - 1) & ~3, FW - 8);
    const int JROWS = min(FH - J0, max(j1 - J0 + 1, 6));        // 6..23
    int NI4 = min(((i1 - I0) >> 2) + 1, (FW - I0) >> 2);        // never OOB
    NI4 = max(NI4, 2);                                           // 2..7

    // ---- P2: per-bin 6-tap windows + weights (14 threads) ----
    if (tid < PH + PW) {
        if (tid < PH) {
            const int ph = tid;
            const float ya = y1 + ph * bin_h, yb = ya + bin_h;
            const int base = min(max((int)floorf(ya) - 1, J0), J0 + JROWS - 6);
            s_bj[ph] = base - J0;
#pragma unroll
            for (int k = 0; k < 6; ++k) {
                const float g = (float)(base + k);
                s_wy[ph][k] = hat_int(yb, g) - hat_int(ya, g);  // 0 outside support
            }
        } else {
            const int pw = tid - PH;
            const float xa = x1 + pw * bin_w, xb = xa + bin_w;
            const int base = min(max((int)floorf(xa) - 1, I0), I0 + 4 * NI4 - 6);
            const int cb0 = base - I0;                           // patch-rel col
#pragma unroll
            for (int k = 0; k < 6; ++k) {
                const float g = (float)(base + k);
                s_wx[pw][k] = hat_int(xb, g) - hat_int(xa, g);  // 0 outside support
                const int c = cb0 + k;                           // <= 27
                s_xoff[pw][k] = (c >> 2) * 36 + (c & 3) * CB;    // padded col offset
            }
        }
    }

    // ---- P1: stage patch rectangle, channel-fast padded, 4x4 transpose ----
    const float* fb = feat + (size_t)(b * CH + c0) * FH * FW;
    for (int u = tid; u < QN * MAXJ * 7; u += 256) {   // 322 units
        const int q   = u / (MAXJ * 7);                // channel quad 0..1
        const int rem = u - q * (MAXJ * 7);
        const int j   = rem / 7;
        const int i4  = rem - j * 7;
        if (j < JROWS && i4 < NI4) {
            const int ig = I0 + 4 * i4;                // <= FW-4 by construction
            const float* src = fb + ((size_t)(4 * q) * FH + (J0 + j)) * FW + ig;
            const float4 v0 = *(const float4*)(src);
            const float4 v1 = *(const float4*)(src + FH * FW);
            const float4 v2 = *(const float4*)(src + 2 * FH * FW);
            const float4 v3 = *(const float4*)(src + 3 * FH * FW);
            // column 4*i4+k lives at i4*36 + k*8 (+4q for the quad)
            float* dst = &patch[(size_t)j * RS + i4 * 36 + 4 * q];
            *(float4*)(dst + 0 * CB) = make_float4(v0.x, v1.x, v2.x, v3.x);
            *(float4*)(dst + 1 * CB) = make_float4(v0.y, v1.y, v2.y, v3.y);
            *(float4*)(dst + 2 * CB) = make_float4(v0.z, v1.z, v2.z, v3.z);
            *(float4*)(dst + 3 * CB) = make_float4(v0.w, v1.w, v2.w, v3.w);
        }
    }
    __syncthreads();

    // ---- PA: rs[pw][j][c8] = sum_i wx * patch, uniform 6 taps ----
    for (int u = tid; u < JROWS * 14; u += 256) {      // <= 322 units
        const int j   = u / 14;
        const int rem = u - j * 14;
        const int pw  = rem >> 1;                      // 0..6
        const int q   = rem & 1;                       // channel quad
        int   xo[6];
        float wx[6];
#pragma unroll
        for (int k = 0; k < 6; ++k) { xo[k] = s_xoff[pw][k]; wx[k] = s_wx[pw][k]; }
        const float* base = &patch[(size_t)j * RS + 4 * q];
        float ax = 0.0f, ay = 0.0f, az = 0.0f, aw = 0.0f;
#pragma unroll
        for (int ii = 0; ii < 6; ++ii) {
            const float w = wx[ii];
            const float4 v = *(const float4*)(base + xo[ii]);
            ax += w * v.x; ay += w * v.y; az += w * v.z; aw += w * v.w;
        }
        *(float4*)(&rs[(size_t)pw * RSJ + j * CB + 4 * q]) =
            make_float4(ax, ay, az, aw);
    }
    __syncthreads();

    // ---- PB: combine over rows, float2 channel-pairs; all 4 waves active ----
    const int bin = tid & 63;                          // 49 active per wave
    const int cp  = tid >> 6;                          // channel pair 0..3
    if (bin < NBINS) {
        const int ph = bin / PW;
        const int pw = bin - ph * PW;
        const int bj = s_bj[ph];
        const float* rbase = &rs[(size_t)pw * RSJ + bj * CB + 2 * cp];
        float ax = 0.0f, ay = 0.0f;
#pragma unroll
        for (int jj = 0; jj < 6; ++jj) {
            const float w = s_wy[ph][jj];
            const float2 v = *(const float2*)(rbase + jj * CB);
            ax += w * v.x; ay += w * v.y;
        }
        float* o = out + ((size_t)r * CH + c0 + 2 * cp) * NBINS + bin;
        o[0]     = ax * inv_area;
        o[NBINS] = ay * inv_area;
    }
}

extern "C" void kernel_launch(void* const* d_in, const int* in_sizes, int n_in,
                              void* d_out, int out_size, void* d_ws, size_t ws_size,
                              hipStream_t stream) {
    const float* feat = (const float*)d_in[0];
    const float* rois = (const float*)d_in[1];
    float* out = (float*)d_out;

    prroi_fused<<<dim3(CH / CB, RNUM), 256, 0, stream>>>(feat, rois, out);
}

// Round 10
// 87.789 us; speedup vs baseline: 1.0792x; 1.0792x over previous
//
#include <hip/hip_runtime.h>

// PrRoIPool2D forward, MI355X. B=8, C=256, H=W=48, R=300, 7x7 bins, scale=1/16.
// R10: per-ROI params hoisted into a prep kernel (d_ws table, 448 B/roi).
// Main kernel: no P2 phase, no LDS weight tables; PA/PB weights prefetched
// into registers BEFORE the first barrier (latency hidden behind P1 staging).
// Phases: P1 stage patch [j][i][c8] -> PA row-sums rs[pw][j][c8] -> PB combine.
// LDS 25.8 KB -> 6 blocks/CU.

#define PH 7
#define PW 7
#define NBINS 49
#define SCALE 0.0625f
#define CH 256
#define FH 48
#define FW 48
#define RNUM 300
#define CB 8                 // channels per block
#define QN 2                 // channel quads per block
#define MAXJ 23              // max patch rows
#define ROWF 28              // max patch row width (floats)
#define PRM 112              // param stride per roi (floats)
// param layout: [0+ph*6]: wy[7][6] | [42+pw*6]: wx[7][6] | [84+ph]: bj (int)
// [91+pw]: bi (int) | [98]: inv_area | [99]: b | [100]: J0 | [101]: I0
// [102]: JROWS | [103]: NI4   (ints stored as float bit patterns)

__device__ __forceinline__ float hat_int(float x, float g) {
    float t = x - (g - 1.0f);
    if (t <= 0.0f) return 0.0f;
    if (t <= 1.0f) return 0.5f * t * t;
    if (t <= 2.0f) { float u = 2.0f - t; return 1.0f - 0.5f * u * u; }
    return 1.0f;
}

// ---- prep: per-roi windows/weights/bounds, once ----
__global__ __launch_bounds__(256)
void prroi_prep(const float* __restrict__ rois, float* __restrict__ prm) {
    const int r = blockIdx.x * 4 + (threadIdx.x >> 6);
    const int t = threadIdx.x & 63;
    if (r >= RNUM || t >= 15) return;

    const float* roi = rois + r * 5;
    const int   b  = (int)roi[0];
    const float x1 = roi[1] * SCALE, y1 = roi[2] * SCALE;
    const float x2 = roi[3] * SCALE, y2 = roi[4] * SCALE;
    const float roi_w = fmaxf(x2 - x1, 0.0f), roi_h = fmaxf(y2 - y1, 0.0f);
    const float bin_w = roi_w / (float)PW, bin_h = roi_h / (float)PH;
    const float area = bin_w * bin_h;
    const float inv_area = (area > 0.0f) ? (1.0f / area) : 0.0f;

    const float ylo = fminf(y1, y2), yhi = fmaxf(y1, y2);
    const float xlo = fminf(x1, x2), xhi = fmaxf(x1, x2);
    const int j1 = min(FH - 1, (int)floorf(yhi) + 1);
    const int i1 = min(FW - 1, (int)floorf(xhi) + 1);
    const int J0 = min(max(0, (int)floorf(ylo) - 1), FH - 6);
    const int I0 = min(max(0, (int)floorf(xlo) - 1) & ~3, FW - 8);
    const int JROWS = min(FH - J0, max(j1 - J0 + 1, 6));        // 6..23
    int NI4 = min(((i1 - I0) >> 2) + 1, (FW - I0) >> 2);
    NI4 = max(NI4, 2);                                           // 2..7

    float* p = prm + (size_t)r * PRM;
    if (t < PH) {
        const int ph = t;
        const float ya = y1 + ph * bin_h, yb = ya + bin_h;
        const int base = min(max((int)floorf(ya) - 1, J0), J0 + JROWS - 6);
        p[84 + ph] = __int_as_float(base - J0);
#pragma unroll
        for (int k = 0; k < 6; ++k) {
            const float g = (float)(base + k);
            p[ph * 6 + k] = hat_int(yb, g) - hat_int(ya, g);    // 0 outside support
        }
    } else if (t < PH + PW) {
        const int pw = t - PH;
        const float xa = x1 + pw * bin_w, xb = xa + bin_w;
        const int base = min(max((int)floorf(xa) - 1, I0), I0 + 4 * NI4 - 6);
        p[91 + pw] = __int_as_float(base - I0);
#pragma unroll
        for (int k = 0; k < 6; ++k) {
            const float g = (float)(base + k);
            p[42 + pw * 6 + k] = hat_int(xb, g) - hat_int(xa, g);
        }
    } else {                                                     // t == 14
        p[98]  = inv_area;
        p[99]  = __int_as_float(b);
        p[100] = __int_as_float(J0);
        p[101] = __int_as_float(I0);
        p[102] = __int_as_float(JROWS);
        p[103] = __int_as_float(NI4);
    }
}

// ---- main ----
__global__ __launch_bounds__(256)
void prroi_main(const float* __restrict__ feat,
                const float* __restrict__ prm,
                float* __restrict__ out) {
    const int cblk = blockIdx.x;        // 0..31
    const int r    = blockIdx.y;        // 0..299
    const int c0   = cblk * CB;
    const int tid  = threadIdx.x;

    __shared__ float patch[MAXJ * ROWF * CB];   // [j][i][c8] 20608 B
    __shared__ float rs[PW * MAXJ * CB];        // [pw][j][c8]  5152 B

    const float* p = prm + (size_t)r * PRM;
    const int b     = __float_as_int(p[99]);
    const int J0    = __float_as_int(p[100]);
    const int I0    = __float_as_int(p[101]);
    const int JROWS = __float_as_int(p[102]);
    const int NI4   = __float_as_int(p[103]);

    // ---- prefetch PA params (units v1 = tid, v2 = tid + 256) ----
    const int nA = JROWS * 14;
    const int v1 = tid, v2 = tid + 256;
    int pw1 = 0, q1 = 0, j1r = 0, pw2 = 0, q2 = 0, j2r = 0, bi1 = 0, bi2 = 0;
    float wxa[6], wxb[6];
    const bool a1 = v1 < nA, a2 = v2 < nA;
    if (a1) {
        j1r = v1 / 14; const int rem = v1 - j1r * 14; pw1 = rem >> 1; q1 = rem & 1;
        bi1 = __float_as_int(p[91 + pw1]);
#pragma unroll
        for (int k = 0; k < 6; ++k) wxa[k] = p[42 + pw1 * 6 + k];
    }
    if (a2) {
        j2r = v2 / 14; const int rem = v2 - j2r * 14; pw2 = rem >> 1; q2 = rem & 1;
        bi2 = __float_as_int(p[91 + pw2]);
#pragma unroll
        for (int k = 0; k < 6; ++k) wxb[k] = p[42 + pw2 * 6 + k];
    }

    // ---- prefetch PB params ----
    const int bin = tid & 63;
    const int cp  = tid >> 6;
    float wy[6]; int bj = 0, phv = 0, pwv = 0;
    float inv_area = p[98];
    if (bin < NBINS) {
        phv = bin / PW; pwv = bin - phv * PW;
        bj = __float_as_int(p[84 + phv]);
#pragma unroll
        for (int k = 0; k < 6; ++k) wy[k] = p[phv * 6 + k];
    }

    // ---- P1: stage patch rectangle, channel-fast, 4x4 register transpose ----
    const float* fb = feat + (size_t)(b * CH + c0) * FH * FW;
    for (int u = tid; u < QN * MAXJ * 7; u += 256) {   // 322 units
        const int q   = u / (MAXJ * 7);                // channel quad 0..1
        const int rem = u - q * (MAXJ * 7);
        const int j   = rem / 7;
        const int i4  = rem - j * 7;
        if (j < JROWS && i4 < NI4) {
            const int ig = I0 + 4 * i4;                // <= FW-4 by construction
            const float* src = fb + ((size_t)(4 * q) * FH + (J0 + j)) * FW + ig;
            const float4 v0 = *(const float4*)(src);
            const float4 v1v = *(const float4*)(src + FH * FW);
            const float4 v2v = *(const float4*)(src + 2 * FH * FW);
            const float4 v3v = *(const float4*)(src + 3 * FH * FW);
            float* dst = &patch[((size_t)j * ROWF + 4 * i4) * CB + 4 * q];
            *(float4*)(dst + 0 * CB) = make_float4(v0.x, v1v.x, v2v.x, v3v.x);
            *(float4*)(dst + 1 * CB) = make_float4(v0.y, v1v.y, v2v.y, v3v.y);
            *(float4*)(dst + 2 * CB) = make_float4(v0.z, v1v.z, v2v.z, v3v.z);
            *(float4*)(dst + 3 * CB) = make_float4(v0.w, v1v.w, v2v.w, v3v.w);
        }
    }
    __syncthreads();

    // ---- PA: rs[pw][j][c8] = sum_i wx * patch (weights already in regs) ----
    if (a1) {
        const float* base = &patch[((size_t)j1r * ROWF + bi1) * CB + 4 * q1];
        float ax = 0.0f, ay = 0.0f, az = 0.0f, aw = 0.0f;
#pragma unroll
        for (int ii = 0; ii < 6; ++ii) {
            const float w = wxa[ii];
            const float4 v = *(const float4*)(base + ii * CB);
            ax += w * v.x; ay += w * v.y; az += w * v.z; aw += w * v.w;
        }
        *(float4*)(&rs[((size_t)pw1 * MAXJ + j1r) * CB + 4 * q1]) =
            make_float4(ax, ay, az, aw);
    }
    if (a2) {
        const float* base = &patch[((size_t)j2r * ROWF + bi2) * CB + 4 * q2];
        float ax = 0.0f, ay = 0.0f, az = 0.0f, aw = 0.0f;
#pragma unroll
        for (int ii = 0; ii < 6; ++ii) {
            const float w = wxb[ii];
            const float4 v = *(const float4*)(base + ii * CB);
            ax += w * v.x; ay += w * v.y; az += w * v.z; aw += w * v.w;
        }
        *(float4*)(&rs[((size_t)pw2 * MAXJ + j2r) * CB + 4 * q2]) =
            make_float4(ax, ay, az, aw);
    }
    __syncthreads();

    // ---- PB: combine over rows, float2 channel-pairs ----
    if (bin < NBINS) {
        const float* rbase = &rs[((size_t)pwv * MAXJ + bj) * CB + 2 * cp];
        float ax = 0.0f, ay = 0.0f;
#pragma unroll
        for (int jj = 0; jj < 6; ++jj) {
            const float w = wy[jj];
            const float2 v = *(const float2*)(rbase + jj * CB);
            ax += w * v.x; ay += w * v.y;
        }
        float* o = out + ((size_t)r * CH + c0 + 2 * cp) * NBINS + bin;
        o[0]     = ax * inv_area;
        o[NBINS] = ay * inv_area;
    }
}

extern "C" void kernel_launch(void* const* d_in, const int* in_sizes, int n_in,
                              void* d_out, int out_size, void* d_ws, size_t ws_size,
                              hipStream_t stream) {
    const float* feat = (const float*)d_in[0];
    const float* rois = (const float*)d_in[1];
    float* out = (float*)d_out;
    float* prm = (float*)d_ws;   // 300 * 112 * 4 = 134.4 KB

    prroi_prep<<<(RNUM + 3) / 4, 256, 0, stream>>>(rois, prm);
    prroi_main<<<dim3(CH / CB, RNUM), 256, 0, stream>>>(feat, prm, out);
}